// Round 9
// baseline (102.574 us; speedup 1.0000x reference)
//
#include <hip/hip_runtime.h>

#define HW_  4096
#define DQK  131072     // 32*4096 per batch (q or k)
#define DV   1048576    // 256*4096 per batch

using bf16x8 = __attribute__((ext_vector_type(8))) __bf16;
using f32x4  = __attribute__((ext_vector_type(4))) float;

static __device__ __forceinline__ unsigned short f2bf(float f) {
    union { float f; unsigned u; } v; v.f = f;
    unsigned r = v.u + 0x7FFFu + ((v.u >> 16) & 1u);
    return (unsigned short)(r >> 16);
}
static __device__ __forceinline__ float bf2f(unsigned short h) {
    union { unsigned u; float f; } v; v.u = ((unsigned)h) << 16;
    return v.f;
}

// 4x4 in-register transpose across lanes {base..base+3} (2-stage butterfly).
// In: lane holds col (lane&3) of a 4x4 tile, v[i]=row i. Out: lane holds row (lane&3), w[j]=col j.
static __device__ __forceinline__ f32x4 xp4(f32x4 v, bool p0, bool p1) {
    float e01 = p0 ? v[0] : v[1];
    float r01 = __shfl_xor(e01, 1);
    float x0 = p0 ? r01 : v[0];
    float x1 = p0 ? v[1] : r01;
    float e23 = p0 ? v[2] : v[3];
    float r23 = __shfl_xor(e23, 1);
    float x2 = p0 ? r23 : v[2];
    float x3 = p0 ? v[3] : r23;
    float eA = p1 ? x0 : x2;
    float rA = __shfl_xor(eA, 2);
    float w0 = p1 ? rA : x0;
    float w2 = p1 ? x2 : rA;
    float eB = p1 ? x1 : x3;
    float rB = __shfl_xor(eB, 2);
    float w1 = p1 ? rB : x1;
    float w3 = p1 ? x3 : rB;
    return (f32x4){w0, w1, w2, w3};
}

// ---------------- pack weights into MFMA A-fragment layout:
// addr(m,c) = (m>>4)*4096 + (c>>3)*128 + (m&15)*8 + (c&7)
__global__ __launch_bounds__(256) void k_pack(const float* wq, const float* wk, const float* wv,
                                              unsigned short* WhF, unsigned short* WlF, unsigned short* WvF) {
    int idx = blockIdx.x * 256 + threadIdx.x;   // 81920 total
    if (idx < 16384) {
        int i = idx;
        int mt = i >> 12, cg = (i >> 7) & 31, ml = (i >> 3) & 15, cl = i & 7;
        int m = mt * 16 + ml, c = cg * 8 + cl;
        float f = (m < 32) ? wq[m * 256 + c] : wk[(m - 32) * 256 + c];
        unsigned short hi = f2bf(f);
        WhF[i] = hi;
        WlF[i] = f2bf(f - bf2f(hi));
    } else {
        int i = idx - 16384;
        int mt = i >> 12, kt = (i >> 7) & 31, lr = (i >> 3) & 15, j = i & 7;
        int m = mt * 16 + lr, c = kt * 8 + j;
        WvF[i] = f2bf(wv[m * 256 + c]);
    }
}

// ---------------- qk GEMM, split-bf16, NO LDS, no barriers (r5-validated).
__global__ __launch_bounds__(256) void k_gemm_qk(const unsigned short* __restrict__ WhF,
                                                 const unsigned short* __restrict__ WlF,
                                                 const float* __restrict__ x,
                                                 const float* __restrict__ bq, const float* __restrict__ bk,
                                                 float* __restrict__ QF, float* __restrict__ KF) {
    int b  = blockIdx.y;
    int n0 = blockIdx.x * 64;
    int t = threadIdx.x;
    int lane = t & 63, wid = t >> 6;
    int wm = wid & 1, wn = wid >> 1;
    int lr = lane & 15, kg = lane >> 4;

    const float* xb = x + (size_t)b * DV;
    const unsigned short* Ah0 = WhF + (size_t)(wm * 2) * 4096 + lane * 8;
    const unsigned short* Al0 = WlF + (size_t)(wm * 2) * 4096 + lane * 8;

    f32x4 acc[2][2];
    for (int mi = 0; mi < 2; mi++)
        for (int ni = 0; ni < 2; ni++) acc[mi][ni] = (f32x4){0.f, 0.f, 0.f, 0.f};

    for (int kk = 0; kk < 8; kk++) {
        bf16x8 ah[2], al[2];
        for (int mi = 0; mi < 2; mi++) {
            ah[mi] = *(const bf16x8*)(Ah0 + (size_t)mi * 4096 + kk * 512);
            al[mi] = *(const bf16x8*)(Al0 + (size_t)mi * 4096 + kk * 512);
        }
        bf16x8 bh[2], bl[2];
        int cbase = kk * 32 + kg * 8;
        for (int ni = 0; ni < 2; ni++) {
            const float* xp = xb + (size_t)cbase * HW_ + n0 + wn * 32 + ni * 16 + lr;
            #pragma unroll
            for (int j = 0; j < 8; j++) {
                float v = xp[(size_t)j * HW_];
                __bf16 h = (__bf16)v;
                bh[ni][j] = h;
                bl[ni][j] = (__bf16)(v - (float)h);
            }
        }
        for (int mi = 0; mi < 2; mi++)
            for (int ni = 0; ni < 2; ni++) {
                acc[mi][ni] = __builtin_amdgcn_mfma_f32_16x16x32_bf16(ah[mi], bh[ni], acc[mi][ni], 0, 0, 0);
                acc[mi][ni] = __builtin_amdgcn_mfma_f32_16x16x32_bf16(ah[mi], bl[ni], acc[mi][ni], 0, 0, 0);
                acc[mi][ni] = __builtin_amdgcn_mfma_f32_16x16x32_bf16(al[mi], bh[ni], acc[mi][ni], 0, 0, 0);
            }
    }

    float* dst = (wm == 0) ? QF : KF;
    const float* bias = (wm == 0) ? bq : bk;
    for (int mi = 0; mi < 2; mi++) {
        int mq0 = mi * 16 + kg * 4;
        for (int i = 0; i < 4; i++) {
            int mq = mq0 + i;
            float bs = bias[mq];
            for (int ni = 0; ni < 2; ni++) {
                int n = n0 + wn * 32 + ni * 16 + lr;
                dst[(size_t)b * DQK + (size_t)mq * HW_ + n] = acc[mi][ni][i] + bs;
            }
        }
    }
}

// ---------------- scores: 256 blocks, each owns a 512-elem d-slice for ALL 16 batches.
__global__ __launch_bounds__(256) void k_scores2(const float* __restrict__ QF, const float* __restrict__ KF,
                                                 float* __restrict__ Sp) {
    __shared__ float Ql[16][520], Kl[16][520];
    int s = blockIdx.x;
    int m = s >> 3, off = (s & 7) * 512;
    int t = threadIdx.x;
    for (int b = 0; b < 16; b++) {
        const float* qs = QF + (size_t)b * DQK + (size_t)m * HW_ + off;
        const float* ks = KF + (size_t)b * DQK + (size_t)m * HW_ + off;
        Ql[b][t]       = qs[t];
        Ql[b][t + 256] = qs[t + 256];
        Kl[b][t]       = ks[t];
        Kl[b][t + 256] = ks[t + 256];
    }
    __syncthreads();
    int p = t >> 1, h = t & 1;
    int b = p >> 3, j = p & 7;
    int hb = b >> 2, wb = b & 3;
    int bp = (j < 4) ? (j * 4 + wb) : (hb * 4 + (j - 4));
    const f32x4* q4 = (const f32x4*)&Ql[b][h * 256];
    const f32x4* k4 = (const f32x4*)&Kl[bp][h * 256];
    f32x4 a4 = (f32x4){0.f, 0.f, 0.f, 0.f};
    for (int i = 0; i < 64; i++) a4 += q4[i] * k4[i];
    float sres = a4[0] + a4[1] + a4[2] + a4[3];
    sres += __shfl_xor(sres, 1);
    if (h == 0) Sp[(size_t)p * 256 + s] = sres;
}

// ---------------- reduce slices + softmax + fold gamma -> M [0..255] + rowsum [256..271]
__global__ void k_softmax2(const float* __restrict__ Sp, const float* __restrict__ gamma,
                           float* __restrict__ Mm) {
    __shared__ float SS[128];
    int t = threadIdx.x;
    const f32x4* s4 = (const f32x4*)(Sp + (size_t)t * 256);
    f32x4 a = (f32x4){0.f, 0.f, 0.f, 0.f};
    for (int i = 0; i < 64; i++) a += s4[i];
    SS[t] = a[0] + a[1] + a[2] + a[3];
    __syncthreads();
    if (t < 16) {
        int b = t, h = b >> 2, w = b & 3;
        float e[8];
        for (int j = 0; j < 8; j++) e[j] = SS[b * 8 + j];
        e[h] = -INFINITY;
        float mx = e[0];
        for (int j = 1; j < 8; j++) mx = fmaxf(mx, e[j]);
        float aa[8], sum = 0.f;
        for (int j = 0; j < 8; j++) { aa[j] = expf(e[j] - mx); sum += aa[j]; }
        float inv = 1.0f / sum;
        float g = gamma[0];
        float row[16];
        for (int c = 0; c < 16; c++) row[c] = 0.f;
        for (int gg = 0; gg < 4; gg++) if (gg != h) row[gg * 4 + w] += aa[gg] * inv;
        for (int gg = 0; gg < 4; gg++) row[h * 4 + gg] += aa[4 + gg] * inv;
        for (int c = 0; c < 16; c++) Mm[b * 16 + c] = row[c] * g;
        Mm[256 + b] = g;
    }
}

// ---------------- fused v-GEMM + mix + bias + residual.
// Block: 128 m (mhalf via blockIdx.y) x 16 n x 16 b; 512 thr (8 waves); 2 blocks/CU.
// Blocks (x,0),(x,1) have linear ids x, x+256 -> same XCD -> shared x reads in L2.
__global__ __launch_bounds__(512, 4) void k_fused(const unsigned short* __restrict__ WvF,
                                                  const float* __restrict__ x,
                                                  const float* __restrict__ bv,
                                                  const float* __restrict__ Mm,
                                                  float* __restrict__ out) {
    // [buf][bp][row 0..7][17 units of 16B]; row stride 136 elems = 272 B
    __shared__ __align__(16) __bf16 XB[2][16][1088];      // 69632 B -> 2 blocks/CU
    int n0 = blockIdx.x * 16;
    int mhalf = blockIdx.y;
    int t = threadIdx.x;
    int lane = t & 63, wid = t >> 6;      // wid = m-frag within half (8 frags)
    int lr = lane & 15, kg = lane >> 4;
    int n4 = t & 3, sk = (t >> 2) & 63, bpg = t >> 8;     // bpg 0..1, 8 bpi each
    int sigr = ((lr & 3) << 2) | (lr >> 2);

    f32x4 u[16];
    #pragma unroll
    for (int b = 0; b < 16; b++) u[b] = (f32x4){0.f, 0.f, 0.f, 0.f};

    f32x4 xv[8];
    #pragma unroll
    for (int bpi = 0; bpi < 8; bpi++)
        xv[bpi] = *(const f32x4*)(x + (size_t)(bpg * 8 + bpi) * DV + (size_t)sk * HW_ + n0 + n4 * 4);
    {
        int rowoff = (sk >> 3) * 136 + (sk & 7);
        #pragma unroll
        for (int bpi = 0; bpi < 8; bpi++) {
            __bf16* basep = &XB[0][bpg * 8 + bpi][rowoff];
            #pragma unroll
            for (int e = 0; e < 4; e++)
                basep[((e << 2) | n4) * 8] = (__bf16)xv[bpi][e];
        }
    }
    __syncthreads();

    const unsigned short* Wvb = WvF + (size_t)(mhalf * 8 + wid) * 4096 + lane * 8;

    for (int c = 0; c < 4; c++) {
        int cur = c & 1;
        if (c < 3) {
            #pragma unroll
            for (int bpi = 0; bpi < 8; bpi++)
                xv[bpi] = *(const f32x4*)(x + (size_t)(bpg * 8 + bpi) * DV + (size_t)((c + 1) * 64 + sk) * HW_ + n0 + n4 * 4);
        }
        #pragma unroll
        for (int sub = 0; sub < 2; sub++) {
            bf16x8 a = *(const bf16x8*)(Wvb + (c * 2 + sub) * 512);
            const __bf16* bbase = &XB[cur][0][(sub * 4 + kg) * 136 + sigr * 8];
            #pragma unroll
            for (int bp = 0; bp < 16; bp++) {
                bf16x8 bb = *(const bf16x8*)(bbase + bp * 1088);
                u[bp] = __builtin_amdgcn_mfma_f32_16x16x32_bf16(a, bb, u[bp], 0, 0, 0);
            }
        }
        if (c < 3) {
            int nb = cur ^ 1;
            int rowoff = (sk >> 3) * 136 + (sk & 7);
            #pragma unroll
            for (int bpi = 0; bpi < 8; bpi++) {
                __bf16* basep = &XB[nb][bpg * 8 + bpi][rowoff];
                #pragma unroll
                for (int e = 0; e < 4; e++)
                    basep[((e << 2) | n4) * 8] = (__bf16)xv[bpi][e];
            }
        }
        __syncthreads();
    }

    // epilogue: mix (7-sparse) + rs*bv in row-fragment form; 4x4 shuffle transpose ->
    // n-contiguous f32x4; coalesced residual load + out store.
    int mrow0 = mhalf * 128 + wid * 16 + kg * 4;
    f32x4 bv4 = (f32x4){bv[mrow0], bv[mrow0 + 1], bv[mrow0 + 2], bv[mrow0 + 3]};
    bool p0 = (lane & 1) != 0, p1 = (lane & 2) != 0;
    int mrow = mrow0 + (lane & 3);              // row this lane owns post-transpose
    int nq = n0 + (lr >> 2) * 4;                // n-quad this lane owns post-transpose
    #pragma unroll
    for (int b = 0; b < 16; b++) {
        int h = b >> 2, w = b & 3;
        f32x4 mo = (f32x4){0.f, 0.f, 0.f, 0.f};
        #pragma unroll
        for (int g = 0; g < 4; g++) {
            if (g != h) mo += Mm[b * 16 + g * 4 + w] * u[g * 4 + w];
            mo += Mm[b * 16 + h * 4 + g] * u[h * 4 + g];
        }
        mo += Mm[256 + b] * bv4;
        f32x4 wv4 = xp4(mo, p0, p1);
        size_t gidx = (size_t)b * DV + (size_t)mrow * HW_ + nq;
        f32x4 rr = *(const f32x4*)(x + gidx);
        *(f32x4*)(out + gidx) = wv4 + rr;
    }
}

extern "C" void kernel_launch(void* const* d_in, const int* in_sizes, int n_in,
                              void* d_out, int out_size, void* d_ws, size_t ws_size,
                              hipStream_t stream) {
    (void)in_sizes; (void)n_in; (void)out_size; (void)ws_size;
    const float* x     = (const float*)d_in[0];
    const float* wq    = (const float*)d_in[1];
    const float* bq    = (const float*)d_in[2];
    const float* wk    = (const float*)d_in[3];
    const float* bk    = (const float*)d_in[4];
    const float* wv    = (const float*)d_in[5];
    const float* bv    = (const float*)d_in[6];
    const float* gamma = (const float*)d_in[7];

    char* ws = (char*)d_ws;
    // ws layout: WhF 32768 | WlF 32768 | WvF 131072 | QF 8388608 | KF 8388608 | Sp 131072 | Mm 1088
    unsigned short* WhF = (unsigned short*)(ws + 0);
    unsigned short* WlF = (unsigned short*)(ws + 32768);
    unsigned short* WvF = (unsigned short*)(ws + 65536);
    float*          QF  = (float*)(ws + 196608);
    float*          KF  = (float*)(ws + 8585216);
    float*          Sp  = (float*)(ws + 16973824);
    float*          Mm  = (float*)(ws + 17104896);
    float*          vo  = (float*)d_out;

    k_pack     <<<320, 256, 0, stream>>>(wq, wk, wv, WhF, WlF, WvF);
    k_gemm_qk  <<<dim3(64, 16), 256, 0, stream>>>(WhF, WlF, x, bq, bk, QF, KF);
    k_scores2  <<<256, 256, 0, stream>>>(QF, KF, Sp);
    k_softmax2 <<<1, 128, 0, stream>>>(Sp, gamma, Mm);
    k_fused    <<<dim3(256, 2), 512, 0, stream>>>(WvF, x, bv, Mm, vo);
}

// Round 10
// 91.724 us; speedup vs baseline: 1.1183x; 1.1183x over previous
//
#include <hip/hip_runtime.h>

#define HW_  4096
#define DQK  131072     // 32*4096 per batch (q or k)
#define DV   1048576    // 256*4096 per batch

using bf16x8 = __attribute__((ext_vector_type(8))) __bf16;
using f32x4  = __attribute__((ext_vector_type(4))) float;

static __device__ __forceinline__ unsigned short f2bf(float f) {
    union { float f; unsigned u; } v; v.f = f;
    unsigned r = v.u + 0x7FFFu + ((v.u >> 16) & 1u);
    return (unsigned short)(r >> 16);
}
static __device__ __forceinline__ float bf2f(unsigned short h) {
    union { unsigned u; float f; } v; v.u = ((unsigned)h) << 16;
    return v.f;
}

// 4x4 in-register transpose across lanes {4k..4k+3} (r9-validated).
static __device__ __forceinline__ f32x4 xp4(f32x4 v, bool p0, bool p1) {
    float e01 = p0 ? v[0] : v[1];
    float r01 = __shfl_xor(e01, 1);
    float x0 = p0 ? r01 : v[0];
    float x1 = p0 ? v[1] : r01;
    float e23 = p0 ? v[2] : v[3];
    float r23 = __shfl_xor(e23, 1);
    float x2 = p0 ? r23 : v[2];
    float x3 = p0 ? v[3] : r23;
    float eA = p1 ? x0 : x2;
    float rA = __shfl_xor(eA, 2);
    float w0 = p1 ? rA : x0;
    float w2 = p1 ? x2 : rA;
    float eB = p1 ? x1 : x3;
    float rB = __shfl_xor(eB, 2);
    float w1 = p1 ? rB : x1;
    float w3 = p1 ? x3 : rB;
    return (f32x4){w0, w1, w2, w3};
}

// ---------------- pack weights into MFMA A-fragment layout:
// addr(m,c) = (m>>4)*4096 + (c>>3)*128 + (m&15)*8 + (c&7)
__global__ __launch_bounds__(256) void k_pack(const float* wq, const float* wk, const float* wv,
                                              unsigned short* WhF, unsigned short* WlF, unsigned short* WvF) {
    int idx = blockIdx.x * 256 + threadIdx.x;   // 81920 total
    if (idx < 16384) {
        int i = idx;
        int mt = i >> 12, cg = (i >> 7) & 31, ml = (i >> 3) & 15, cl = i & 7;
        int m = mt * 16 + ml, c = cg * 8 + cl;
        float f = (m < 32) ? wq[m * 256 + c] : wk[(m - 32) * 256 + c];
        unsigned short hi = f2bf(f);
        WhF[i] = hi;
        WlF[i] = f2bf(f - bf2f(hi));
    } else {
        int i = idx - 16384;
        int mt = i >> 12, kt = (i >> 7) & 31, lr = (i >> 3) & 15, j = i & 7;
        int m = mt * 16 + lr, c = kt * 8 + j;
        WvF[i] = f2bf(wv[m * 256 + c]);
    }
}

// ---------------- qk GEMM, split-bf16, NO LDS, no barriers (r5-validated).
__global__ __launch_bounds__(256) void k_gemm_qk(const unsigned short* __restrict__ WhF,
                                                 const unsigned short* __restrict__ WlF,
                                                 const float* __restrict__ x,
                                                 const float* __restrict__ bq, const float* __restrict__ bk,
                                                 float* __restrict__ QF, float* __restrict__ KF) {
    int b  = blockIdx.y;
    int n0 = blockIdx.x * 64;
    int t = threadIdx.x;
    int lane = t & 63, wid = t >> 6;
    int wm = wid & 1, wn = wid >> 1;
    int lr = lane & 15, kg = lane >> 4;

    const float* xb = x + (size_t)b * DV;
    const unsigned short* Ah0 = WhF + (size_t)(wm * 2) * 4096 + lane * 8;
    const unsigned short* Al0 = WlF + (size_t)(wm * 2) * 4096 + lane * 8;

    f32x4 acc[2][2];
    for (int mi = 0; mi < 2; mi++)
        for (int ni = 0; ni < 2; ni++) acc[mi][ni] = (f32x4){0.f, 0.f, 0.f, 0.f};

    for (int kk = 0; kk < 8; kk++) {
        bf16x8 ah[2], al[2];
        for (int mi = 0; mi < 2; mi++) {
            ah[mi] = *(const bf16x8*)(Ah0 + (size_t)mi * 4096 + kk * 512);
            al[mi] = *(const bf16x8*)(Al0 + (size_t)mi * 4096 + kk * 512);
        }
        bf16x8 bh[2], bl[2];
        int cbase = kk * 32 + kg * 8;
        for (int ni = 0; ni < 2; ni++) {
            const float* xp = xb + (size_t)cbase * HW_ + n0 + wn * 32 + ni * 16 + lr;
            #pragma unroll
            for (int j = 0; j < 8; j++) {
                float v = xp[(size_t)j * HW_];
                __bf16 h = (__bf16)v;
                bh[ni][j] = h;
                bl[ni][j] = (__bf16)(v - (float)h);
            }
        }
        for (int mi = 0; mi < 2; mi++)
            for (int ni = 0; ni < 2; ni++) {
                acc[mi][ni] = __builtin_amdgcn_mfma_f32_16x16x32_bf16(ah[mi], bh[ni], acc[mi][ni], 0, 0, 0);
                acc[mi][ni] = __builtin_amdgcn_mfma_f32_16x16x32_bf16(ah[mi], bl[ni], acc[mi][ni], 0, 0, 0);
                acc[mi][ni] = __builtin_amdgcn_mfma_f32_16x16x32_bf16(al[mi], bh[ni], acc[mi][ni], 0, 0, 0);
            }
    }

    float* dst = (wm == 0) ? QF : KF;
    const float* bias = (wm == 0) ? bq : bk;
    for (int mi = 0; mi < 2; mi++) {
        int mq0 = mi * 16 + kg * 4;
        for (int i = 0; i < 4; i++) {
            int mq = mq0 + i;
            float bs = bias[mq];
            for (int ni = 0; ni < 2; ni++) {
                int n = n0 + wn * 32 + ni * 16 + lr;
                dst[(size_t)b * DQK + (size_t)mq * HW_ + n] = acc[mi][ni][i] + bs;
            }
        }
    }
}

// ---------------- scores: 256 blocks, each owns a 512-elem d-slice for ALL 16 batches.
__global__ __launch_bounds__(256) void k_scores2(const float* __restrict__ QF, const float* __restrict__ KF,
                                                 float* __restrict__ Sp) {
    __shared__ float Ql[16][520], Kl[16][520];
    int s = blockIdx.x;
    int m = s >> 3, off = (s & 7) * 512;
    int t = threadIdx.x;
    for (int b = 0; b < 16; b++) {
        const float* qs = QF + (size_t)b * DQK + (size_t)m * HW_ + off;
        const float* ks = KF + (size_t)b * DQK + (size_t)m * HW_ + off;
        Ql[b][t]       = qs[t];
        Ql[b][t + 256] = qs[t + 256];
        Kl[b][t]       = ks[t];
        Kl[b][t + 256] = ks[t + 256];
    }
    __syncthreads();
    int p = t >> 1, h = t & 1;
    int b = p >> 3, j = p & 7;
    int hb = b >> 2, wb = b & 3;
    int bp = (j < 4) ? (j * 4 + wb) : (hb * 4 + (j - 4));
    const f32x4* q4 = (const f32x4*)&Ql[b][h * 256];
    const f32x4* k4 = (const f32x4*)&Kl[bp][h * 256];
    f32x4 a4 = (f32x4){0.f, 0.f, 0.f, 0.f};
    for (int i = 0; i < 64; i++) a4 += q4[i] * k4[i];
    float sres = a4[0] + a4[1] + a4[2] + a4[3];
    sres += __shfl_xor(sres, 1);
    if (h == 0) Sp[(size_t)p * 256 + s] = sres;
}

// ---------------- reduce slices + softmax + fold gamma -> M [0..255] + rowsum [256..271]
__global__ void k_softmax2(const float* __restrict__ Sp, const float* __restrict__ gamma,
                           float* __restrict__ Mm) {
    __shared__ float SS[128];
    int t = threadIdx.x;
    const f32x4* s4 = (const f32x4*)(Sp + (size_t)t * 256);
    f32x4 a = (f32x4){0.f, 0.f, 0.f, 0.f};
    for (int i = 0; i < 64; i++) a += s4[i];
    SS[t] = a[0] + a[1] + a[2] + a[3];
    __syncthreads();
    if (t < 16) {
        int b = t, h = b >> 2, w = b & 3;
        float e[8];
        for (int j = 0; j < 8; j++) e[j] = SS[b * 8 + j];
        e[h] = -INFINITY;
        float mx = e[0];
        for (int j = 1; j < 8; j++) mx = fmaxf(mx, e[j]);
        float aa[8], sum = 0.f;
        for (int j = 0; j < 8; j++) { aa[j] = expf(e[j] - mx); sum += aa[j]; }
        float inv = 1.0f / sum;
        float g = gamma[0];
        float row[16];
        for (int c = 0; c < 16; c++) row[c] = 0.f;
        for (int gg = 0; gg < 4; gg++) if (gg != h) row[gg * 4 + w] += aa[gg] * inv;
        for (int gg = 0; gg < 4; gg++) row[h * 4 + gg] += aa[4 + gg] * inv;
        for (int c = 0; c < 16; c++) Mm[b * 16 + c] = row[c] * g;
        Mm[256 + b] = g;
    }
}

// ---------------- mix + transpose + convert, PRE-FRAGMENTED output, 7-sparse M rows (r5-validated).
// Xm addr(b,p,c) = b*DV + (p>>4)*4096 + (c>>3)*128 + (p&15)*8 + (c&7); value = sum_bp M[b][bp]*x[bp][c][p]
__global__ __launch_bounds__(256) void k_mix(const float* __restrict__ Mm, const float* __restrict__ x,
                                             unsigned short* __restrict__ Xm) {
    __shared__ float Ms[256];
    __shared__ unsigned short T[16][32][36];     // [b][p][c]
    using u16x4 = __attribute__((ext_vector_type(4))) unsigned short;
    int t = threadIdx.x;
    int p0 = blockIdx.x * 32, c0 = blockIdx.y * 32;
    Ms[t] = Mm[t];

    int c_l = t >> 3, p4 = t & 7;
    f32x4 in4[16];
    for (int bp = 0; bp < 16; bp++)
        in4[bp] = *(const f32x4*)(x + (size_t)bp * DV + (size_t)(c0 + c_l) * HW_ + p0 + p4 * 4);
    __syncthreads();
    for (int b = 0; b < 16; b++) {
        int h = b >> 2, w = b & 3;
        f32x4 acc = (f32x4){0.f, 0.f, 0.f, 0.f};
        #pragma unroll
        for (int g = 0; g < 4; g++) {
            if (g != h) acc += Ms[b * 16 + g * 4 + w] * in4[g * 4 + w];
            acc += Ms[b * 16 + h * 4 + g] * in4[h * 4 + g];
        }
        for (int e = 0; e < 4; e++) T[b][p4 * 4 + e][c_l] = f2bf(acc[e]);
    }
    __syncthreads();
    int p_l = t >> 3, cq = t & 7;
    int p = p0 + p_l;
    int c = c0 + cq * 4;
    size_t dst = (size_t)(p >> 4) * 4096 + (size_t)(c >> 3) * 128 + (p & 15) * 8 + (c & 7);
    for (int b = 0; b < 16; b++) {
        u16x4 v = *(const u16x4*)&T[b][p_l][cq * 4];
        *(u16x4*)(Xm + (size_t)b * DV + dst) = v;
    }
}

// ---------------- v GEMM + bias + residual: NO LDS, no barriers, 256m x 64n per block.
// All 16 B-frags hoisted (max MLP); A prefetched 1 k-step ahead; xp4-transposed coalesced
// epilogue with nontemporal out stores.
__global__ __launch_bounds__(512) void k_gemm_v_res(const unsigned short* __restrict__ WvF,
                                                    const unsigned short* __restrict__ XmF,
                                                    const float* __restrict__ bv,
                                                    const float* __restrict__ MmRs,
                                                    const float* __restrict__ x,
                                                    float* __restrict__ out) {
    int b  = blockIdx.y;
    int n0 = blockIdx.x * 64;
    int t = threadIdx.x;
    int lane = t & 63, wid = t >> 6;
    int wm = wid >> 1, wn = wid & 1;          // 4 m-waves x 2 n-waves; wave tile 64m x 32n
    int lr = lane & 15, kg = lane >> 4;

    const unsigned short* Bb = XmF + (size_t)b * DV + (size_t)(blockIdx.x * 4 + wn * 2) * 4096 + lane * 8;
    const unsigned short* Ab = WvF + (size_t)(wm * 4) * 4096 + lane * 8;

    // hoist ALL B fragments (16 loads in flight)
    bf16x8 bfr[8][2];
    #pragma unroll
    for (int kk = 0; kk < 8; kk++)
        #pragma unroll
        for (int ni = 0; ni < 2; ni++)
            bfr[kk][ni] = *(const bf16x8*)(Bb + (size_t)ni * 4096 + kk * 512);

    f32x4 acc[4][2];
    #pragma unroll
    for (int mi = 0; mi < 4; mi++)
        for (int ni = 0; ni < 2; ni++) acc[mi][ni] = (f32x4){0.f, 0.f, 0.f, 0.f};

    bf16x8 a[4], an[4];
    #pragma unroll
    for (int mi = 0; mi < 4; mi++) a[mi] = *(const bf16x8*)(Ab + (size_t)mi * 4096);
    #pragma unroll
    for (int kk = 0; kk < 8; kk++) {
        if (kk < 7) {
            #pragma unroll
            for (int mi = 0; mi < 4; mi++)
                an[mi] = *(const bf16x8*)(Ab + (size_t)mi * 4096 + (kk + 1) * 512);
        }
        #pragma unroll
        for (int mi = 0; mi < 4; mi++)
            #pragma unroll
            for (int ni = 0; ni < 2; ni++)
                acc[mi][ni] = __builtin_amdgcn_mfma_f32_16x16x32_bf16(a[mi], bfr[kk][ni], acc[mi][ni], 0, 0, 0);
        #pragma unroll
        for (int mi = 0; mi < 4; mi++) a[mi] = an[mi];
    }

    float rs = MmRs[256 + b];
    bool p0 = (lane & 1) != 0, p1 = (lane & 2) != 0;
    #pragma unroll
    for (int mi = 0; mi < 4; mi++) {
        int mrow0 = wm * 64 + mi * 16 + kg * 4;
        f32x4 bvv = *(const f32x4*)(bv + mrow0);
        int mrow = mrow0 + (lane & 3);
        #pragma unroll
        for (int ni = 0; ni < 2; ni++) {
            f32x4 mo = acc[mi][ni] + rs * bvv;
            f32x4 w4 = xp4(mo, p0, p1);
            int nq = n0 + wn * 32 + ni * 16 + (lr >> 2) * 4;
            size_t g = (size_t)b * DV + (size_t)mrow * HW_ + nq;
            f32x4 rr = *(const f32x4*)(x + g);
            __builtin_nontemporal_store(w4 + rr, (f32x4*)(out + g));
        }
    }
}

extern "C" void kernel_launch(void* const* d_in, const int* in_sizes, int n_in,
                              void* d_out, int out_size, void* d_ws, size_t ws_size,
                              hipStream_t stream) {
    (void)in_sizes; (void)n_in; (void)out_size; (void)ws_size;
    const float* x     = (const float*)d_in[0];
    const float* wq    = (const float*)d_in[1];
    const float* bq    = (const float*)d_in[2];
    const float* wk    = (const float*)d_in[3];
    const float* bk    = (const float*)d_in[4];
    const float* wv    = (const float*)d_in[5];
    const float* bv    = (const float*)d_in[6];
    const float* gamma = (const float*)d_in[7];

    char* ws = (char*)d_ws;
    // ws layout: WhF 32768 | WlF 32768 | WvF 131072 | QF 8388608 | KF 8388608 | Xm 33554432
    // Aliases (lifetime-disjoint): Mm@0 (WhF dead after qk); Sp@Xm-start (dead before mix writes).
    unsigned short* WhF = (unsigned short*)(ws + 0);
    unsigned short* WlF = (unsigned short*)(ws + 32768);
    unsigned short* WvF = (unsigned short*)(ws + 65536);
    float*          QF  = (float*)(ws + 196608);
    float*          KF  = (float*)(ws + 8585216);
    unsigned short* Xm  = (unsigned short*)(ws + 16973824);  // 33554432 -> total 50528256
    float*          Sp  = (float*)(ws + 16973824);           // aliases Xm (dead before mix)
    float*          Mm  = (float*)(ws + 0);                  // aliases WhF (dead by then)
    float*          vo  = (float*)d_out;

    k_pack       <<<320, 256, 0, stream>>>(wq, wk, wv, WhF, WlF, WvF);
    k_gemm_qk    <<<dim3(64, 16), 256, 0, stream>>>(WhF, WlF, x, bq, bk, QF, KF);
    k_scores2    <<<256, 256, 0, stream>>>(QF, KF, Sp);
    k_softmax2   <<<1, 128, 0, stream>>>(Sp, gamma, Mm);
    k_mix        <<<dim3(128, 8), 256, 0, stream>>>(Mm, x, Xm);
    k_gemm_v_res <<<dim3(64, 16), 512, 0, stream>>>(WvF, Xm, bv, Mm, x, vo);
}

// Round 11
// 85.954 us; speedup vs baseline: 1.1934x; 1.0671x over previous
//
#include <hip/hip_runtime.h>

#define HW_  4096
#define DQK  131072     // 32*4096 per batch (q or k)
#define DV   1048576    // 256*4096 per batch

using bf16x8 = __attribute__((ext_vector_type(8))) __bf16;
using f32x4  = __attribute__((ext_vector_type(4))) float;
using u16x8  = __attribute__((ext_vector_type(8))) unsigned short;

static __device__ __forceinline__ unsigned short f2bf(float f) {
    union { float f; unsigned u; } v; v.f = f;
    unsigned r = v.u + 0x7FFFu + ((v.u >> 16) & 1u);
    return (unsigned short)(r >> 16);
}
static __device__ __forceinline__ float bf2f(unsigned short h) {
    union { unsigned u; float f; } v; v.u = ((unsigned)h) << 16;
    return v.f;
}

// ---------------- pack weights into MFMA A-fragment layout:
// addr(m,c) = (m>>4)*4096 + (c>>3)*128 + (m&15)*8 + (c&7)
__global__ __launch_bounds__(256) void k_pack(const float* wq, const float* wk, const float* wv,
                                              unsigned short* WhF, unsigned short* WlF, unsigned short* WvF) {
    int idx = blockIdx.x * 256 + threadIdx.x;   // 81920 total
    if (idx < 16384) {
        int i = idx;
        int mt = i >> 12, cg = (i >> 7) & 31, ml = (i >> 3) & 15, cl = i & 7;
        int m = mt * 16 + ml, c = cg * 8 + cl;
        float f = (m < 32) ? wq[m * 256 + c] : wk[(m - 32) * 256 + c];
        unsigned short hi = f2bf(f);
        WhF[i] = hi;
        WlF[i] = f2bf(f - bf2f(hi));
    } else {
        int i = idx - 16384;
        int mt = i >> 12, kt = (i >> 7) & 31, lr = (i >> 3) & 15, j = i & 7;
        int m = mt * 16 + lr, c = kt * 8 + j;
        WvF[i] = f2bf(wv[m * 256 + c]);
    }
}

// ---------------- qk GEMM, split-bf16, NO LDS, no barriers.
// QF/KF stored in FLAT block-local layout (coalesced 1KB/wave f32x4 stores):
// flat = b*DQK + nblk*2048 + slot*256 + lane*4 + i   (identical mapping for q and k).
__global__ __launch_bounds__(256) void k_gemm_qk(const unsigned short* __restrict__ WhF,
                                                 const unsigned short* __restrict__ WlF,
                                                 const float* __restrict__ x,
                                                 const float* __restrict__ bq, const float* __restrict__ bk,
                                                 float* __restrict__ QF, float* __restrict__ KF) {
    int b  = blockIdx.y;
    int n0 = blockIdx.x * 64;
    int t = threadIdx.x;
    int lane = t & 63, wid = t >> 6;
    int wm = wid & 1, wn = wid >> 1;
    int lr = lane & 15, kg = lane >> 4;

    const float* xb = x + (size_t)b * DV;
    const unsigned short* Ah0 = WhF + (size_t)(wm * 2) * 4096 + lane * 8;
    const unsigned short* Al0 = WlF + (size_t)(wm * 2) * 4096 + lane * 8;

    f32x4 acc[2][2];
    for (int mi = 0; mi < 2; mi++)
        for (int ni = 0; ni < 2; ni++) acc[mi][ni] = (f32x4){0.f, 0.f, 0.f, 0.f};

    for (int kk = 0; kk < 8; kk++) {
        bf16x8 ah[2], al[2];
        for (int mi = 0; mi < 2; mi++) {
            ah[mi] = *(const bf16x8*)(Ah0 + (size_t)mi * 4096 + kk * 512);
            al[mi] = *(const bf16x8*)(Al0 + (size_t)mi * 4096 + kk * 512);
        }
        bf16x8 bh[2], bl[2];
        int cbase = kk * 32 + kg * 8;
        for (int ni = 0; ni < 2; ni++) {
            const float* xp = xb + (size_t)cbase * HW_ + n0 + wn * 32 + ni * 16 + lr;
            #pragma unroll
            for (int j = 0; j < 8; j++) {
                float v = xp[(size_t)j * HW_];
                __bf16 h = (__bf16)v;
                bh[ni][j] = h;
                bl[ni][j] = (__bf16)(v - (float)h);
            }
        }
        for (int mi = 0; mi < 2; mi++)
            for (int ni = 0; ni < 2; ni++) {
                acc[mi][ni] = __builtin_amdgcn_mfma_f32_16x16x32_bf16(ah[mi], bh[ni], acc[mi][ni], 0, 0, 0);
                acc[mi][ni] = __builtin_amdgcn_mfma_f32_16x16x32_bf16(ah[mi], bl[ni], acc[mi][ni], 0, 0, 0);
                acc[mi][ni] = __builtin_amdgcn_mfma_f32_16x16x32_bf16(al[mi], bh[ni], acc[mi][ni], 0, 0, 0);
            }
    }

    float* dst = (wm == 0) ? QF : KF;
    const float* bias = (wm == 0) ? bq : bk;
    size_t base = (size_t)b * DQK + (size_t)blockIdx.x * 2048;
    for (int mi = 0; mi < 2; mi++) {
        f32x4 bvv = *(const f32x4*)(bias + mi * 16 + kg * 4);   // bvv[i] = bias[mi*16+kg*4+i]
        for (int ni = 0; ni < 2; ni++) {
            int slot = (wn * 2 + ni) * 2 + mi;
            f32x4 v = acc[mi][ni] + bvv;
            *(f32x4*)(dst + base + slot * 256 + lane * 4) = v;
        }
    }
}

// ---------------- scores: 256 blocks, each owns a flat 512-elem slice for ALL 16 batches.
// QF/KF layout-agnostic: dot over identical flat indices.
__global__ __launch_bounds__(256) void k_scores2(const float* __restrict__ QF, const float* __restrict__ KF,
                                                 float* __restrict__ Sp) {
    __shared__ float Ql[16][520], Kl[16][520];
    int s = blockIdx.x;
    size_t off = (size_t)s * 512;
    int t = threadIdx.x;
    for (int b = 0; b < 16; b++) {
        const float* qs = QF + (size_t)b * DQK + off;
        const float* ks = KF + (size_t)b * DQK + off;
        Ql[b][t]       = qs[t];
        Ql[b][t + 256] = qs[t + 256];
        Kl[b][t]       = ks[t];
        Kl[b][t + 256] = ks[t + 256];
    }
    __syncthreads();
    int p = t >> 1, h = t & 1;
    int b = p >> 3, j = p & 7;
    int hb = b >> 2, wb = b & 3;
    int bp = (j < 4) ? (j * 4 + wb) : (hb * 4 + (j - 4));
    const f32x4* q4 = (const f32x4*)&Ql[b][h * 256];
    const f32x4* k4 = (const f32x4*)&Kl[bp][h * 256];
    f32x4 a4 = (f32x4){0.f, 0.f, 0.f, 0.f};
    for (int i = 0; i < 64; i++) a4 += q4[i] * k4[i];
    float sres = a4[0] + a4[1] + a4[2] + a4[3];
    sres += __shfl_xor(sres, 1);
    if (h == 0) Sp[(size_t)p * 256 + s] = sres;
}

// ---------------- reduce slices + softmax + fold gamma -> M [0..255] + rowsum [256..271]
__global__ void k_softmax2(const float* __restrict__ Sp, const float* __restrict__ gamma,
                           float* __restrict__ Mm) {
    __shared__ float SS[128];
    int t = threadIdx.x;
    const f32x4* s4 = (const f32x4*)(Sp + (size_t)t * 256);
    f32x4 a = (f32x4){0.f, 0.f, 0.f, 0.f};
    for (int i = 0; i < 64; i++) a += s4[i];
    SS[t] = a[0] + a[1] + a[2] + a[3];
    __syncthreads();
    if (t < 16) {
        int b = t, h = b >> 2, w = b & 3;
        float e[8];
        for (int j = 0; j < 8; j++) e[j] = SS[b * 8 + j];
        e[h] = -INFINITY;
        float mx = e[0];
        for (int j = 1; j < 8; j++) mx = fmaxf(mx, e[j]);
        float aa[8], sum = 0.f;
        for (int j = 0; j < 8; j++) { aa[j] = expf(e[j] - mx); sum += aa[j]; }
        float inv = 1.0f / sum;
        float g = gamma[0];
        float row[16];
        for (int c = 0; c < 16; c++) row[c] = 0.f;
        for (int gg = 0; gg < 4; gg++) if (gg != h) row[gg * 4 + w] += aa[gg] * inv;
        for (int gg = 0; gg < 4; gg++) row[h * 4 + gg] += aa[4 + gg] * inv;
        for (int c = 0; c < 16; c++) Mm[b * 16 + c] = row[c] * g;
        Mm[256 + b] = g;
    }
}

// ---------------- mix + transpose + convert, PRE-FRAGMENTED Xm (same layout as r10),
// phase-B writes regrouped: 16 consecutive lanes write 16 consecutive p -> 256-B runs.
__global__ __launch_bounds__(256) void k_mix(const float* __restrict__ Mm, const float* __restrict__ x,
                                             unsigned short* __restrict__ Xm) {
    __shared__ float Ms[256];
    __shared__ __align__(16) unsigned short T[16][32][40];   // 40-short rows: 16B-aligned octs
    int t = threadIdx.x;
    int p0 = blockIdx.x * 32, c0 = blockIdx.y * 32;
    Ms[t] = Mm[t];

    int c_l = t >> 3, p4 = t & 7;
    f32x4 in4[16];
    for (int bp = 0; bp < 16; bp++)
        in4[bp] = *(const f32x4*)(x + (size_t)bp * DV + (size_t)(c0 + c_l) * HW_ + p0 + p4 * 4);
    __syncthreads();
    for (int b = 0; b < 16; b++) {
        int h = b >> 2, w = b & 3;
        f32x4 acc = (f32x4){0.f, 0.f, 0.f, 0.f};
        #pragma unroll
        for (int g = 0; g < 4; g++) {
            if (g != h) acc += Ms[b * 16 + g * 4 + w] * in4[g * 4 + w];
            acc += Ms[b * 16 + h * 4 + g] * in4[h * 4 + g];
        }
        for (int e = 0; e < 4; e++) T[b][p4 * 4 + e][c_l] = f2bf(acc[e]);
    }
    __syncthreads();
    // phase B: thread (p_l, co, bh): one 16-B store per b; lanes 0..15 -> p 0..15 (256-B run)
    int p_l = t & 31, co = (t >> 5) & 3, bh = t >> 7;
    int p = p0 + p_l;
    int c = c0 + co * 8;
    size_t dst = (size_t)(p >> 4) * 4096 + (size_t)(c >> 3) * 128 + (p & 15) * 8;
    #pragma unroll
    for (int bi = 0; bi < 8; bi++) {
        int b = bh * 8 + bi;
        u16x8 v = *(const u16x8*)&T[b][p_l][co * 8];
        *(u16x8*)(Xm + (size_t)b * DV + dst) = v;
    }
}

// ---------------- v GEMM + bias + residual: NO-LDS k-loop (hoisted B, prefetched A);
// epilogue staged through LDS -> full-row 256-B residual reads + nontemporal out stores.
__global__ __launch_bounds__(512) void k_gemm_v_res(const unsigned short* __restrict__ WvF,
                                                    const unsigned short* __restrict__ XmF,
                                                    const float* __restrict__ bv,
                                                    const float* __restrict__ MmRs,
                                                    const float* __restrict__ x,
                                                    float* __restrict__ out) {
    __shared__ __align__(16) float LD[256][68];   // 69632 B
    int b  = blockIdx.y;
    int n0 = blockIdx.x * 64;
    int t = threadIdx.x;
    int lane = t & 63, wid = t >> 6;
    int wm = wid >> 1, wn = wid & 1;          // 4 m-waves x 2 n-waves; wave tile 64m x 32n
    int lr = lane & 15, kg = lane >> 4;

    const unsigned short* Bb = XmF + (size_t)b * DV + (size_t)(blockIdx.x * 4 + wn * 2) * 4096 + lane * 8;
    const unsigned short* Ab = WvF + (size_t)(wm * 4) * 4096 + lane * 8;

    bf16x8 bfr[8][2];
    #pragma unroll
    for (int kk = 0; kk < 8; kk++)
        #pragma unroll
        for (int ni = 0; ni < 2; ni++)
            bfr[kk][ni] = *(const bf16x8*)(Bb + (size_t)ni * 4096 + kk * 512);

    f32x4 acc[4][2];
    #pragma unroll
    for (int mi = 0; mi < 4; mi++)
        for (int ni = 0; ni < 2; ni++) acc[mi][ni] = (f32x4){0.f, 0.f, 0.f, 0.f};

    bf16x8 a[4], an[4];
    #pragma unroll
    for (int mi = 0; mi < 4; mi++) a[mi] = *(const bf16x8*)(Ab + (size_t)mi * 4096);
    #pragma unroll
    for (int kk = 0; kk < 8; kk++) {
        if (kk < 7) {
            #pragma unroll
            for (int mi = 0; mi < 4; mi++)
                an[mi] = *(const bf16x8*)(Ab + (size_t)mi * 4096 + (kk + 1) * 512);
        }
        #pragma unroll
        for (int mi = 0; mi < 4; mi++)
            #pragma unroll
            for (int ni = 0; ni < 2; ni++)
                acc[mi][ni] = __builtin_amdgcn_mfma_f32_16x16x32_bf16(a[mi], bfr[kk][ni], acc[mi][ni], 0, 0, 0);
        #pragma unroll
        for (int mi = 0; mi < 4; mi++) a[mi] = an[mi];
    }

    float rs = MmRs[256 + b];
    #pragma unroll
    for (int mi = 0; mi < 4; mi++) {
        int mrow0 = wm * 64 + mi * 16 + kg * 4;
        f32x4 bvv = *(const f32x4*)(bv + mrow0);
        #pragma unroll
        for (int ni = 0; ni < 2; ni++) {
            f32x4 mo = acc[mi][ni] + rs * bvv;
            int ncol = wn * 32 + ni * 16 + lr;
            #pragma unroll
            for (int i = 0; i < 4; i++) LD[mrow0 + i][ncol] = mo[i];
        }
    }
    __syncthreads();
    // each wave streams 32 rows: per pass 4 rows x 64 cols (256-B segments)
    #pragma unroll
    for (int ps = 0; ps < 8; ps++) {
        int row = wid * 32 + ps * 4 + (lane >> 4);
        int nc  = (lane & 15) * 4;
        f32x4 o = *(const f32x4*)&LD[row][nc];
        size_t g = (size_t)b * DV + (size_t)row * HW_ + n0 + nc;
        f32x4 rr = *(const f32x4*)(x + g);
        __builtin_nontemporal_store(o + rr, (f32x4*)(out + g));
    }
}

extern "C" void kernel_launch(void* const* d_in, const int* in_sizes, int n_in,
                              void* d_out, int out_size, void* d_ws, size_t ws_size,
                              hipStream_t stream) {
    (void)in_sizes; (void)n_in; (void)out_size; (void)ws_size;
    const float* x     = (const float*)d_in[0];
    const float* wq    = (const float*)d_in[1];
    const float* bq    = (const float*)d_in[2];
    const float* wk    = (const float*)d_in[3];
    const float* bk    = (const float*)d_in[4];
    const float* wv    = (const float*)d_in[5];
    const float* bv    = (const float*)d_in[6];
    const float* gamma = (const float*)d_in[7];

    char* ws = (char*)d_ws;
    // ws layout: WhF 32768 | WlF 32768 | WvF 131072 | QF 8388608 | KF 8388608 | Xm 33554432
    // Aliases (lifetime-disjoint): Mm@0 (WhF dead after qk); Sp@Xm-start (dead before mix writes).
    unsigned short* WhF = (unsigned short*)(ws + 0);
    unsigned short* WlF = (unsigned short*)(ws + 32768);
    unsigned short* WvF = (unsigned short*)(ws + 65536);
    float*          QF  = (float*)(ws + 196608);
    float*          KF  = (float*)(ws + 8585216);
    unsigned short* Xm  = (unsigned short*)(ws + 16973824);  // 33554432 -> total 50528256
    float*          Sp  = (float*)(ws + 16973824);           // aliases Xm (dead before mix)
    float*          Mm  = (float*)(ws + 0);                  // aliases WhF (dead by then)
    float*          vo  = (float*)d_out;

    k_pack       <<<320, 256, 0, stream>>>(wq, wk, wv, WhF, WlF, WvF);
    k_gemm_qk    <<<dim3(64, 16), 256, 0, stream>>>(WhF, WlF, x, bq, bk, QF, KF);
    k_scores2    <<<256, 256, 0, stream>>>(QF, KF, Sp);
    k_softmax2   <<<1, 128, 0, stream>>>(Sp, gamma, Mm);
    k_mix        <<<dim3(128, 8), 256, 0, stream>>>(Mm, x, Xm);
    k_gemm_v_res <<<dim3(64, 16), 512, 0, stream>>>(WvF, Xm, bv, Mm, x, vo);
}